// Round 6
// baseline (267.059 us; speedup 1.0000x reference)
//
#include <hip/hip_runtime.h>
#include <math.h>

// Problem constants (fixed by the reference)
constexpr int Bn  = 32;
constexpr int Cn  = 256;
constexpr int Hn  = 64;
constexpr int Wn  = 64;
constexpr int HW  = Hn * Wn;        // 4096
constexpr int CHW = Cn * HW;        // 1048576
constexpr int HW4 = HW / 4;         // 1024 float4 per (b,c) plane

// Tiling: block = (batch, 4-row stripe). 512 blocks x 256 threads, 2/CU.
constexpr int RG   = 4;             // output rows per block
constexpr int NRG  = Hn / RG;       // 16 row-groups
constexpr int LR   = RG + 6;        // 10 window rows (3-row halo each side)
constexpr int LC   = 72;            // 64 + col halo, padded
constexpr int GRID = Bn * NRG;      // 512

typedef float f4_t __attribute__((ext_vector_type(4)));

// -------------------------------------------------------------------------
// Single fused kernel. The conv's cross-block dependency is only a 3-row
// halo, so each block RECOMPUTES the pooled max/avg for its 10-row window
// directly from x instead of synchronizing (grid.sync measured structurally
// dead on MI355X: rounds 1-2, ~70-250us/barrier). Redundancy is 2.5x on the
// pooled read, but repeats are L3-hits (round-1 FETCH counters proved L3
// absorbs x re-reads completely: 133 MB fetched for 2 logical passes).
//
// Phase A: pooled max/avg of the halo window. 160 threads own one float4
//   column chunk each; per channel the block reads 10 rows x 256 B =
//   2.5 KB CONTIGUOUS (row stride is 256 B), i.e. 1 KiB/wave-instr -- the
//   same proven-coalesced pattern as the old reduce_k. Results -> LDS
//   [10][72], zero-padded -> branchless conv.
// Phase B: conv+sigmoid, one position/thread (wave-uniform row, consecutive
//   cols -> conflict-free LDS reads). Scale -> LDS (1 KB).
// Phase C: wave w streams channels [w*64,w*64+64); lane's float4 scale in
//   REGISTERS for all 64 iterations; x rows are L2-hot (phase A just read
//   them); out stores nontemporal (never re-read; x+out = 268 MB > L3,
//   protect x residency).
// -------------------------------------------------------------------------
__global__ __launch_bounds__(256) void fused_k(const float* __restrict__ x,
                                               const float* __restrict__ w,
                                               float* __restrict__ out) {
    __shared__ float spm[LR][LC];     // pooled-max window (zero-padded)
    __shared__ float spa[LR][LC];     // pooled-avg window
    __shared__ float ssc[RG * Wn];    // scale for the block's 256 positions
    __shared__ float sw[98];

    const int tid  = threadIdx.x;
    const int b    = blockIdx.x >> 4;            // batch
    const int rg   = blockIdx.x & (NRG - 1);     // row-group
    const int row0 = rg * RG;

    if (tid < 98) sw[tid] = w[tid];
    // Zero-fill window (borders must be 0 for branchless conv).
    for (int i = tid; i < LR * LC; i += 256) {
        ((float*)spm)[i] = 0.f;
        ((float*)spa)[i] = 0.f;
    }
    __syncthreads();

    // ---- Phase A: pooled max/avg for rows row0-3 .. row0+6 --------------
    if (tid < LR * 16) {
        const int lr = tid >> 4;                 // window row 0..9
        const int c4 = tid & 15;                 // float4 col chunk 0..15
        const int gh = row0 - 3 + lr;
        if (gh >= 0 && gh < Hn) {
            const float4* xp = (const float4*)x + (size_t)b * (CHW / 4)
                               + gh * 16 + c4;
            float4 mx = make_float4(-INFINITY, -INFINITY, -INFINITY, -INFINITY);
            float4 sm = make_float4(0.f, 0.f, 0.f, 0.f);
            #pragma unroll 8
            for (int c = 0; c < Cn; ++c) {
                float4 v = xp[(size_t)c * HW4];
                mx.x = fmaxf(mx.x, v.x); mx.y = fmaxf(mx.y, v.y);
                mx.z = fmaxf(mx.z, v.z); mx.w = fmaxf(mx.w, v.w);
                sm.x += v.x; sm.y += v.y; sm.z += v.z; sm.w += v.w;
            }
            const float inv = 1.0f / (float)Cn;
            const int cb = 3 + c4 * 4;
            spm[lr][cb + 0] = mx.x; spm[lr][cb + 1] = mx.y;
            spm[lr][cb + 2] = mx.z; spm[lr][cb + 3] = mx.w;
            spa[lr][cb + 0] = sm.x * inv; spa[lr][cb + 1] = sm.y * inv;
            spa[lr][cb + 2] = sm.z * inv; spa[lr][cb + 3] = sm.w * inv;
        }
    }
    __syncthreads();

    // ---- Phase B: 7x7 conv + sigmoid, one position per thread -----------
    {
        const int hl  = tid >> 6;                // local row 0..3 (wave id)
        const int col = tid & 63;
        float acc = 0.f;
        #pragma unroll
        for (int kh = 0; kh < 7; ++kh) {
            #pragma unroll
            for (int kw = 0; kw < 7; ++kw) {
                acc += spm[hl + kh][col + kw] * sw[kh * 7 + kw]
                     + spa[hl + kh][col + kw] * sw[49 + kh * 7 + kw];
            }
        }
        ssc[tid] = 1.f / (1.f + expf(-acc));
    }
    __syncthreads();

    // ---- Phase C: stream multiply, wave w -> channels [w*64, w*64+64) ---
    const int wv   = tid >> 6;
    const int lane = tid & 63;
    const float4 s = ((const float4*)ssc)[lane];

    const float4* x4 = (const float4*)x;
    float4* o4 = (float4*)out;

    size_t idx = (size_t)b * (CHW / 4) + (size_t)(wv * 64) * HW4
               + rg * 64 + lane;
    #pragma unroll 4
    for (int k = 0; k < 64; ++k, idx += HW4) {
        const float4 v = x4[idx];
        f4_t o;
        o.x = v.x * s.x; o.y = v.y * s.y;
        o.z = v.z * s.z; o.w = v.w * s.w;
        __builtin_nontemporal_store(o, (f4_t*)&o4[idx]);
    }
}

extern "C" void kernel_launch(void* const* d_in, const int* in_sizes, int n_in,
                              void* d_out, int out_size, void* d_ws, size_t ws_size,
                              hipStream_t stream) {
    const float* x = (const float*)d_in[0];
    const float* w = (const float*)d_in[1];
    float* out = (float*)d_out;

    // Single dispatch: 512 blocks x 256 threads.
    fused_k<<<GRID, 256, 0, stream>>>(x, w, out);
}

// Round 7
// 266.247 us; speedup vs baseline: 1.0030x; 1.0030x over previous
//
#include <hip/hip_runtime.h>
#include <math.h>

// Problem constants (fixed by the reference)
constexpr int Bn  = 32;
constexpr int Cn  = 256;
constexpr int Hn  = 64;
constexpr int Wn  = 64;
constexpr int HW  = Hn * Wn;        // 4096
constexpr int CHW = Cn * HW;        // 1048576
constexpr int HW4 = HW / 4;         // 1024 float4 per (b,c) plane
constexpr int NPOS  = Bn * HW;      // 131072 spatial positions
constexpr int NPOS4 = NPOS / 4;     // 32768 float4 positions

// convmul tiling: block = (batch, 4-row stripe, channel-half).
constexpr int CM_ROWS  = 4;                  // rows per stripe
constexpr int CM_LR    = CM_ROWS + 6;        // 10 LDS rows (3-row halo)
constexpr int CM_LC    = 72;                 // 64 + col halo, padded
constexpr int CM_NCG   = 2;                  // channel halves
constexpr int CM_CH    = Cn / CM_NCG;        // 128 channels per block
constexpr int CM_CHW   = CM_CH / 4;          // 32 channels per wave
constexpr int CM_GRID  = Bn * (Hn / CM_ROWS) * CM_NCG;   // 1024 blocks

typedef float f4_t __attribute__((ext_vector_type(4)));

// -------------------------------------------------------------------------
// Kernel 1: channel-wise max + mean. (round-0 version, byte-identical: the
// best-measured artifact; r3's 512-thread variant regressed.)
// Block = 256 threads = 4 waves. Wave `chunk` reduces channels
// [chunk*64, chunk*64+64) for 64 consecutive float4 spatial positions.
// Each load: 64 lanes x 16 B contiguous = 1 KiB coalesced; 64 loads/thread
// unroll-8 -> ~8 KB in flight/CU, right at the HBM latency-coverage knee.
// NOTE (r1/r2): cooperative grid.sync fusion structurally dead on MI355X
// (~70-250us/barrier, scales with block count).
// NOTE (r6): single-kernel fusion with per-block pooled RECOMPUTE is worse
// (113us vs 84.5us): concurrent halo re-reads are NOT L3-absorbed
// (FETCH 223 MB = 1.67x) and 160-active-thread phase ran latency-bound at
// 3.2 TB/s. The split structure + back-to-back L3 reuse wins.
// -------------------------------------------------------------------------
__global__ __launch_bounds__(256) void reduce_k(const float* __restrict__ x,
                                                float* __restrict__ pmax,
                                                float* __restrict__ pavg) {
    __shared__ float4 smax[4][64];
    __shared__ float4 ssum[4][64];

    const int lane  = threadIdx.x & 63;
    const int chunk = threadIdx.x >> 6;           // 0..3 (wave id)
    const int pos4  = blockIdx.x * 64 + lane;     // global float4 position
    const int b     = pos4 >> 10;                 // / HW4 (block never straddles b)
    const int sp4   = pos4 & (HW4 - 1);

    const float4* xp = (const float4*)x + (size_t)b * (CHW / 4)
                       + (size_t)(chunk * 64) * HW4 + sp4;

    float4 mx = make_float4(-INFINITY, -INFINITY, -INFINITY, -INFINITY);
    float4 sm = make_float4(0.f, 0.f, 0.f, 0.f);

    #pragma unroll 8
    for (int c = 0; c < 64; ++c) {
        float4 v = xp[(size_t)c * HW4];
        mx.x = fmaxf(mx.x, v.x); mx.y = fmaxf(mx.y, v.y);
        mx.z = fmaxf(mx.z, v.z); mx.w = fmaxf(mx.w, v.w);
        sm.x += v.x; sm.y += v.y; sm.z += v.z; sm.w += v.w;
    }

    smax[chunk][lane] = mx;
    ssum[chunk][lane] = sm;
    __syncthreads();

    if (chunk == 0) {
        float4 M = smax[0][lane];
        float4 S = ssum[0][lane];
        #pragma unroll
        for (int k = 1; k < 4; ++k) {
            float4 m2 = smax[k][lane];
            float4 s2 = ssum[k][lane];
            M.x = fmaxf(M.x, m2.x); M.y = fmaxf(M.y, m2.y);
            M.z = fmaxf(M.z, m2.z); M.w = fmaxf(M.w, m2.w);
            S.x += s2.x; S.y += s2.y; S.z += s2.z; S.w += s2.w;
        }
        const float inv = 1.0f / (float)Cn;
        float4 A = make_float4(S.x * inv, S.y * inv, S.z * inv, S.w * inv);
        ((float4*)pmax)[pos4] = M;
        ((float4*)pavg)[pos4] = A;
    }
}

// -------------------------------------------------------------------------
// Kernel 2: fused 7x7 conv + sigmoid + broadcast multiply.
// r7 change vs r5 (single variable): channel dimension split 2-way ->
// 1024 blocks (4/CU, 16 waves/CU) and stream unroll 8. r6 showed the
// streaming phases run latency-bound below ~9 KB in flight/CU; this gives
// ~32 KB. The stripe stage+conv prologue is recomputed once per channel
// half (2x, ~2us aggregate -- LDS-only, hidden under other blocks' streams).
//   1. Stage pmax/pavg halo window (10x70, zero-padded) -> LDS [10][72],
//      branchless conv.
//   2. Each thread: conv+sigmoid for ONE position (wave-uniform row,
//      consecutive cols -> conflict-free LDS).
//   3. Wave w streams channels [cg*128 + w*32, +32); lane's float4 scale
//      in REGISTERS across all 32 iterations; 1 KiB/instr coalesced.
// out stores nontemporal: never re-read, x+out (268 MB) > L3 (256 MB) --
// protect x residency for the back-to-back reuse from kernel 1.
// -------------------------------------------------------------------------
__global__ __launch_bounds__(256) void convmul_k(const float* __restrict__ x,
                                                 const float* __restrict__ pmax,
                                                 const float* __restrict__ pavg,
                                                 const float* __restrict__ w,
                                                 float* __restrict__ out) {
    __shared__ float spm[CM_LR][CM_LC];   // pooled-max window (zero-padded)
    __shared__ float spa[CM_LR][CM_LC];   // pooled-avg window
    __shared__ float ssc[256];            // scale for the block's 256 positions
    __shared__ float sw[98];

    const int tid = threadIdx.x;
    const int bid = blockIdx.x;
    const int cg   = bid & (CM_NCG - 1);         // channel half 0..1
    const int rg   = (bid >> 1) & 15;            // row-group 0..15
    const int b    = bid >> 5;                   // batch 0..31
    const int row0 = rg * CM_ROWS;

    if (tid < 98) sw[tid] = w[tid];

    // ---- Stage halo window (rows row0-3..row0+6, cols -3..68; OOB -> 0) --
    const float* pm = pmax + b * HW;
    const float* pa = pavg + b * HW;
    for (int i = tid; i < CM_LR * CM_LC; i += 256) {
        const int lr = i / CM_LC;
        const int lc = i % CM_LC;
        const int gh = row0 - 3 + lr;
        const int gw = lc - 3;
        const bool ok = (gh >= 0) && (gh < Hn) && (gw >= 0) && (gw < Wn);
        spm[lr][lc] = ok ? pm[gh * Wn + gw] : 0.f;
        spa[lr][lc] = ok ? pa[gh * Wn + gw] : 0.f;
    }
    __syncthreads();

    // ---- Conv + sigmoid: one position per thread, branchless ------------
    {
        const int hl  = tid >> 6;         // local row 0..3 (== wave id)
        const int col = tid & 63;
        float acc = 0.f;
        #pragma unroll
        for (int kh = 0; kh < 7; ++kh) {
            #pragma unroll
            for (int kw = 0; kw < 7; ++kw) {
                acc += spm[hl + kh][col + kw] * sw[kh * 7 + kw]
                     + spa[hl + kh][col + kw] * sw[49 + kh * 7 + kw];
            }
        }
        ssc[tid] = 1.f / (1.f + expf(-acc));
    }
    __syncthreads();

    // ---- Stream: wave w covers channels [cg*128 + w*32, +32) ------------
    const int wv   = tid >> 6;
    const int lane = tid & 63;

    const float4 s = ((const float4*)ssc)[lane];   // scale for lane's 4 cols

    const float4* x4 = (const float4*)x;
    float4* o4 = (float4*)out;

    size_t idx = (size_t)b * (CHW / 4)
               + (size_t)(cg * CM_CH + wv * CM_CHW) * HW4
               + rg * 64 + lane;
    #pragma unroll 8
    for (int k = 0; k < CM_CHW; ++k, idx += HW4) {
        const float4 v = x4[idx];
        f4_t o;
        o.x = v.x * s.x; o.y = v.y * s.y;
        o.z = v.z * s.z; o.w = v.w * s.w;
        __builtin_nontemporal_store(o, (f4_t*)&o4[idx]);
    }
}

extern "C" void kernel_launch(void* const* d_in, const int* in_sizes, int n_in,
                              void* d_out, int out_size, void* d_ws, size_t ws_size,
                              hipStream_t stream) {
    const float* x = (const float*)d_in[0];
    const float* w = (const float*)d_in[1];
    float* out = (float*)d_out;

    // Workspace layout (floats): pmax[NPOS] | pavg[NPOS]  = 1 MB
    float* pmax = (float*)d_ws;
    float* pavg = pmax + NPOS;

    // Pass 1: channel max/mean. 512 blocks x 256 thr (4 waves, 64-ch chunks).
    reduce_k<<<NPOS4 / 64, 256, 0, stream>>>(x, pmax, pavg);

    // Pass 2: fused conv + sigmoid + multiply. 1024 blocks x 256 thr.
    convmul_k<<<CM_GRID, 256, 0, stream>>>(x, pmax, pavg, w, out);
}